// Round 9
// baseline (4006.912 us; speedup 1.0000x reference)
//
#include <hip/hip_runtime.h>

// LSTM: T=512, B=64, I=512, H=512, gates 4H=2048. Inputs fp32, output fp32.
// TWO-PHASE:
//  Kernel A (xproj_kernel, 512 blocks): x@W_ih^T + b_ih + b_hh for all T,
//    stored in the consumer block's exact MFMA C-fragment layout (fp32, 256 MB
//    in d_ws). Fully parallel — removes x streaming + cvt VALU + HBM jitter
//    from the recurrent serial chain.
//  Kernel B (lstm_fused, 64 persistent blocks x 256): recurrence only.
//    Block b owns h-cols [8b,8b+8); W_hh slice in LDS as bf16 B-fragments.
//    h published per-step as compact 1 KB/producer slices (coherent 8B
//    write-through stores / 8B loads, batch-preloaded); per-step aggregated
//    counter polled by one lane per block.
// Fallback: if ws_size < 269 MB, kernel B computes x-proj in-loop (round-8 path).

#define T_STEPS 512
#define BATCH   64
#define HID     512
#define NB      64
#define CNT_STRIDE 16   // uints; 64 B between per-step counters

typedef short bf16x8 __attribute__((ext_vector_type(8)));
typedef float f32x4  __attribute__((ext_vector_type(4)));

struct U16B { unsigned long long x, y; };

__device__ __forceinline__ unsigned short f2bf(float f) {
    unsigned int u = __builtin_bit_cast(unsigned int, f);
    u += 0x7FFFu + ((u >> 16) & 1u);
    return (unsigned short)(u >> 16);
}
__device__ __forceinline__ unsigned int pack2(float lo, float hi) {
    return (unsigned int)f2bf(lo) | ((unsigned int)f2bf(hi) << 16);
}
// load 8 consecutive fp32 from p, round to bf16, pack into 16 B
__device__ __forceinline__ uint4 cvt8(const float* __restrict__ p) {
    float4 f0 = *(const float4*)p;
    float4 f1 = *(const float4*)(p + 4);
    uint4 r;
    r.x = pack2(f0.x, f0.y);
    r.y = pack2(f0.z, f0.w);
    r.z = pack2(f1.x, f1.y);
    r.w = pack2(f1.z, f1.w);
    return r;
}
// coherent write-through 16-byte store as 2x8B relaxed agent atomics
__device__ __forceinline__ void store_cg16(void* p, uint4 v) {
    unsigned long long* q = (unsigned long long*)p;
    U16B u = __builtin_bit_cast(U16B, v);
    __hip_atomic_store(q,     u.x, __ATOMIC_RELAXED, __HIP_MEMORY_SCOPE_AGENT);
    __hip_atomic_store(q + 1, u.y, __ATOMIC_RELAXED, __HIP_MEMORY_SCOPE_AGENT);
}
__device__ __forceinline__ float sigmoidf_(float x) {
    return 1.0f / (1.0f + __expf(-x));
}
__device__ __forceinline__ float tanhf_(float x) {
    x = fminf(fmaxf(x, -15.f), 15.f);
    float e = __expf(2.0f * x);
    return (e - 1.0f) / (e + 1.0f);
}

// ===================== Kernel A: x-projection precompute =====================
// grid = 512 blocks: colblk = bid & 63 (consumer block), tslice = bid >> 6.
// xp layout: [t][colblk][nt(2)][w(4)][lane(64)] float4  (2048 floats per (t,blk))
extern "C" __global__ void __launch_bounds__(256, 1)
xproj_kernel(const float* __restrict__ x,
             const float* __restrict__ W_ih,
             const float* __restrict__ b_ih,
             const float* __restrict__ b_hh,
             float* __restrict__ xp)
{
    __shared__ uint4 sBi[2][16][64];

    const int bid    = blockIdx.x;
    const int colblk = bid & 63;
    const int t0     = (bid >> 6) << 6;   // tslice * 64
    const int tid    = threadIdx.x;
    const int w      = tid >> 6;
    const int lane   = tid & 63;
    const int l15    = lane & 15;
    const int quad   = lane >> 4;
    const int hc0    = colblk * 8;

    for (int u = tid; u < 2 * 16 * 64; u += 256) {
        int nt   = u >> 10;
        int kk   = (u >> 6) & 15;
        int ln   = u & 63;
        int c    = (ln & 15) + (nt << 4);
        int grow = ((c >> 3) << 9) + hc0 + (c & 7);
        int k0   = kk * 32 + ((ln >> 4) << 3);
        sBi[nt][kk][ln] = cvt8(W_ih + grow * 512 + k0);
    }
    float bias0, bias1;
    {
        int c0 = l15,      g0 = ((c0 >> 3) << 9) + hc0 + (c0 & 7);
        int c1 = l15 + 16, g1 = ((c1 >> 3) << 9) + hc0 + (c1 & 7);
        bias0 = b_ih[g0] + b_hh[g0];
        bias1 = b_ih[g1] + b_hh[g1];
    }
    __syncthreads();

    const int aoff = (((w << 4) + l15) * 512) + (quad << 3);

    for (int t = t0; t < t0 + 64; ++t) {
        f32x4 acc0 = {0.f, 0.f, 0.f, 0.f};
        f32x4 acc1 = {0.f, 0.f, 0.f, 0.f};
        const float* xt = x + (size_t)t * (BATCH * 512) + aoff;
#pragma unroll
        for (int kk = 0; kk < 16; ++kk) {
            bf16x8 a  = __builtin_bit_cast(bf16x8, cvt8(xt + kk * 32));
            bf16x8 b0 = __builtin_bit_cast(bf16x8, sBi[0][kk][lane]);
            bf16x8 b1 = __builtin_bit_cast(bf16x8, sBi[1][kk][lane]);
            acc0 = __builtin_amdgcn_mfma_f32_16x16x32_bf16(a, b0, acc0, 0, 0, 0);
            acc1 = __builtin_amdgcn_mfma_f32_16x16x32_bf16(a, b1, acc1, 0, 0, 0);
        }
#pragma unroll
        for (int r = 0; r < 4; ++r) { acc0[r] += bias0; acc1[r] += bias1; }

        float* dst = xp + ((size_t)t * NB + colblk) * 2048 + (w << 8) + (lane << 2);
        *(float4*)dst          = __builtin_bit_cast(float4, acc0);   // nt=0
        *(float4*)(dst + 1024) = __builtin_bit_cast(float4, acc1);   // nt=1
    }
}

// ===================== Kernel B: recurrence ==================================
extern "C" __global__ void __launch_bounds__(256, 1)
lstm_fused(const float* __restrict__ x,
           const float* __restrict__ W_ih,
           const float* __restrict__ W_hh,
           const float* __restrict__ b_ih,
           const float* __restrict__ b_hh,
           float* __restrict__ out,
           unsigned int* __restrict__ cnt,      // [T_STEPS][CNT_STRIDE]
           unsigned short* __restrict__ hbuf,   // [2][NB][64 rows][8 cols] bf16
           const float* __restrict__ xp,        // precomputed x-proj (C-layout)
           int use_xp)
{
    __shared__ uint4 sB[2][2][16][64];
    __shared__ __align__(16) unsigned short sH[4][16][8];   // bf16 (h publish)
    __shared__ __align__(16) float          sHf[4][16][8];  // fp32 (out stores)

    const int blk  = blockIdx.x;
    const int tid  = threadIdx.x;
    const int w    = tid >> 6;
    const int lane = tid & 63;
    const int l15  = lane & 15;
    const int quad = lane >> 4;
    const int hc0  = blk * 8;

    for (int u = tid; u < 2 * 16 * 64; u += 256) {
        int nt   = u >> 10;
        int kk   = (u >> 6) & 15;
        int ln   = u & 63;
        int c    = (ln & 15) + (nt << 4);
        int grow = ((c >> 3) << 9) + hc0 + (c & 7);
        int k0   = kk * 32 + ((ln >> 4) << 3);
        sB[1][nt][kk][ln] = cvt8(W_hh + grow * 512 + k0);
        if (!use_xp) sB[0][nt][kk][ln] = cvt8(W_ih + grow * 512 + k0);
    }

    float bias0 = 0.f, bias1 = 0.f;
    if (!use_xp) {
        int c0 = l15,      g0 = ((c0 >> 3) << 9) + hc0 + (c0 & 7);
        int c1 = l15 + 16, g1 = ((c1 >> 3) << 9) + hc0 + (c1 & 7);
        bias0 = b_ih[g0] + b_hh[g0];
        bias1 = b_ih[g1] + b_hh[g1];
    }
    __syncthreads();

    float cst[4] = {0.f, 0.f, 0.f, 0.f};
    const int aoff = (((w << 4) + l15) * 512) + (quad << 3);
    char* const hb_base = (char*)hbuf;
    const int   hread_off = (quad << 10) + (((w << 4) + l15) << 4);
    long long budget = 300000LL;

    for (int t = 0; t < T_STEPS; ++t) {
        f32x4 acc0 = {0.f, 0.f, 0.f, 0.f};
        f32x4 acc1 = {0.f, 0.f, 0.f, 0.f};

        if (use_xp) {
            // acc init from precomputed x-proj (bias folded); loads overlap poll
            const float* xb = xp + ((size_t)t * NB + blk) * 2048
                              + (w << 8) + (lane << 2);
            float4 xv0 = *(const float4*)xb;
            float4 xv1 = *(const float4*)(xb + 1024);
            acc0 = __builtin_bit_cast(f32x4, xv0);
            acc1 = __builtin_bit_cast(f32x4, xv1);
        } else {
            const float* xt = x + (size_t)t * (BATCH * 512) + aoff;
#pragma unroll
            for (int kk = 0; kk < 16; ++kk) {
                bf16x8 a  = __builtin_bit_cast(bf16x8, cvt8(xt + kk * 32));
                bf16x8 b0 = __builtin_bit_cast(bf16x8, sB[0][0][kk][lane]);
                bf16x8 b1 = __builtin_bit_cast(bf16x8, sB[0][1][kk][lane]);
                acc0 = __builtin_amdgcn_mfma_f32_16x16x32_bf16(a, b0, acc0, 0, 0, 0);
                acc1 = __builtin_amdgcn_mfma_f32_16x16x32_bf16(a, b1, acc1, 0, 0, 0);
            }
        }

        if (t > 0) {
            if (tid == 0) {
                const unsigned int* cp = cnt + (size_t)(t - 1) * CNT_STRIDE;
                while (budget > 0) {
                    unsigned int v = __hip_atomic_load(cp, __ATOMIC_RELAXED,
                                                       __HIP_MEMORY_SCOPE_AGENT);
                    if (v >= NB) break;
                    __builtin_amdgcn_s_sleep(1);
                    --budget;
                }
            }
            __syncthreads();

            // batch-preload all h fragments (32 coherent 8B loads in flight)
            const char* hp = hb_base + (((t - 1) & 1) << 16) + hread_off;
            U16B ha[16];
#pragma unroll
            for (int kk = 0; kk < 16; ++kk) {
                const unsigned long long* q =
                    (const unsigned long long*)(hp + (kk << 12));
                ha[kk].x = __hip_atomic_load(q,     __ATOMIC_RELAXED,
                                             __HIP_MEMORY_SCOPE_AGENT);
                ha[kk].y = __hip_atomic_load(q + 1, __ATOMIC_RELAXED,
                                             __HIP_MEMORY_SCOPE_AGENT);
            }
#pragma unroll
            for (int kk = 0; kk < 16; ++kk) {
                bf16x8 a  = __builtin_bit_cast(bf16x8, ha[kk]);
                bf16x8 b0 = __builtin_bit_cast(bf16x8, sB[1][0][kk][lane]);
                bf16x8 b1 = __builtin_bit_cast(bf16x8, sB[1][1][kk][lane]);
                acc0 = __builtin_amdgcn_mfma_f32_16x16x32_bf16(a, b0, acc0, 0, 0, 0);
                acc1 = __builtin_amdgcn_mfma_f32_16x16x32_bf16(a, b1, acc1, 0, 0, 0);
            }
        }

        // gates; C-layout: col = lane&15, row = quad*4 + reg
        float gi[4], gf[4], gg[4], go[4];
#pragma unroll
        for (int r = 0; r < 4; ++r) {
            float a0 = acc0[r] + bias0;
            float a1 = acc1[r] + bias1;
            float p0 = __shfl_xor(a0, 8, 64);
            float p1 = __shfl_xor(a1, 8, 64);
            gi[r] = a0; gg[r] = a1; gf[r] = p0; go[r] = p1;
        }
        if (l15 < 8) {
#pragma unroll
            for (int r = 0; r < 4; ++r) {
                float iv = sigmoidf_(gi[r]);
                float fv = sigmoidf_(gf[r]);
                float gv = tanhf_(gg[r]);
                float ov = sigmoidf_(go[r]);
                cst[r] = fv * cst[r] + iv * gv;
                float hv = ov * tanhf_(cst[r]);
                sH [w][(quad << 2) + r][l15] = f2bf(hv);
                sHf[w][(quad << 2) + r][l15] = hv;
            }
        }
        asm volatile("s_waitcnt lgkmcnt(0)" ::: "memory");
        if (lane < 16) {
            uint4 v = *(const uint4*)&sH[w][lane][0];
            char* dst = hb_base + ((t & 1) << 16) + (blk << 10)
                        + (((w << 4) + lane) << 4);
            store_cg16(dst, v);
        }
        asm volatile("s_waitcnt vmcnt(0)" ::: "memory");
        __syncthreads();
        if (tid == 0) {
            (void)__hip_atomic_fetch_add(cnt + (size_t)t * CNT_STRIDE, 1u,
                                         __ATOMIC_RELAXED, __HIP_MEMORY_SCOPE_AGENT);
        }

        // fp32 output stores: coalesced, off the critical chain
        if (lane < 32) {
            int row  = lane & 15;
            int half = lane >> 4;
            uint4 v = *(const uint4*)&sHf[w][row][half << 2];
            float* op = out + (size_t)t * (BATCH * HID)
                        + (size_t)((w << 4) + row) * HID + hc0 + (half << 2);
            *(uint4*)op = v;
        }
    }
}

extern "C" void kernel_launch(void* const* d_in, const int* in_sizes, int n_in,
                              void* d_out, int out_size, void* d_ws, size_t ws_size,
                              hipStream_t stream) {
    const float* x    = (const float*)d_in[0];
    const float* W_ih = (const float*)d_in[1];
    const float* W_hh = (const float*)d_in[2];
    const float* b_ih = (const float*)d_in[3];
    const float* b_hh = (const float*)d_in[4];
    float* out = (float*)d_out;

    const size_t cnt_bytes  = (size_t)T_STEPS * CNT_STRIDE * sizeof(unsigned int); // 32 KB
    const size_t hbuf_bytes = (size_t)2 * NB * 64 * 8 * sizeof(unsigned short);    // 128 KB
    const size_t xp_bytes   = (size_t)T_STEPS * NB * 2048 * sizeof(float);         // 256 MB

    unsigned int*   cnt  = (unsigned int*)d_ws;
    unsigned short* hbuf = (unsigned short*)((char*)d_ws + cnt_bytes);
    float*          xp   = (float*)((char*)d_ws + cnt_bytes + hbuf_bytes);

    const int use_xp = (ws_size >= cnt_bytes + hbuf_bytes + xp_bytes) ? 1 : 0;

    (void)hipMemsetAsync(cnt, 0, cnt_bytes, stream);

    if (use_xp) {
        hipLaunchKernelGGL(xproj_kernel, dim3(512), dim3(256), 0, stream,
                           x, W_ih, b_ih, b_hh, xp);
    }
    hipLaunchKernelGGL(lstm_fused, dim3(NB), dim3(256), 0, stream,
                       x, W_ih, W_hh, b_ih, b_hh, out, cnt, hbuf, xp, use_xp);
}